// Round 4
// baseline (276.603 us; speedup 1.0000x reference)
//
#include <hip/hip_runtime.h>

#define NB 128
#define NC 12
#define NL 1024
#define NDIL 7
#define NDIV 2
#define NH 32
#define NK 8
#define NKSZ 9
#define NNCP 6
#define OUTPB (NDIL*NDIV*2*NH*NK)   // 7168

// LDS layout: [Z0 256][g0 1024][Z1 256][g1 1024][Z2 256][g2 1024][Z3 256][g3 1024][Z4 256]
// Zero regions are shared: Zi is wave (i-1)'s back pad AND wave i's front pad.
#define SER_STRIDE 1280
#define LDS_FLOATS (4*SER_STRIDE + 256)   // 5376 floats = 21504 B

__device__ __forceinline__ float4 ld4(const float* p) { return *(const float4*)p; }

// Trees grouped for v_max3/v_min3 fusion; binning in 2-instr accumulate form.
__device__ __forceinline__ void argbin(const float (&a)[NK], bool ok,
                                       float (&cm)[NK], unsigned (&cn)[NK]) {
    float m0 = fmaxf(fmaxf(a[0], a[1]), a[2]);
    float m1 = fmaxf(fmaxf(a[3], a[4]), a[5]);
    float m2 = fmaxf(a[6], a[7]);
    const float mx = fmaxf(fmaxf(m0, m1), m2);
    float n0 = fminf(fminf(a[0], a[1]), a[2]);
    float n1 = fminf(fminf(a[3], a[4]), a[5]);
    float n2 = fminf(a[6], a[7]);
    const float mn = fminf(fminf(n0, n1), n2);
    if (ok) {
        #pragma unroll
        for (int k = 0; k < NK; ++k) {
            cm[k] = (a[k] == mx) ? cm[k] + a[k] : cm[k];
            cn[k] = (a[k] == mn) ? cn[k] + 1u  : cn[k];
        }
    }
}

__global__ __launch_bounds__(256) void hydra_kernel(
    const float* __restrict__ X,   // [B, C, L]
    const float* __restrict__ W,   // [NDIL, NDIV, K*H, 1, KSZ]
    const int*   __restrict__ I,   // [NDIL, NDIV, H, NCP]
    float*       __restrict__ out) // [B, 28*H*K]
{
    __shared__ float lds[LDS_FLOATS];
    __shared__ float red[4][16];

    const int bid = blockIdx.x;
    const int h4 = bid & 7;
    const int dj = (bid >> 3) % 14;
    const int b  = (bid >> 3) / 14;
    const int di = dj >> 1;
    const int j  = dj & 1;
    const int d  = 1 << di;

    const int tid  = threadIdx.x;
    const int lane = tid & 63;
    const int wid  = __builtin_amdgcn_readfirstlane(tid >> 6);
    const int h    = h4 * 4 + wid;            // wave-uniform
    const int Sw   = 256 + wid * SER_STRIDE;  // wave series base (logical idx)

    // --- zero all pad regions (each thread: 5 stores) ---------------------
    #pragma unroll
    for (int z = 0; z < 5; ++z) lds[z * SER_STRIDE + tid] = 0.f;

    // --- wave-uniform weights (scalarize to SGPRs) ------------------------
    const float* Wp = W + (size_t)((di*NDIV + j)*(NK*NH) + h*NK) * NKSZ;
    float w[NK][NKSZ];
    #pragma unroll
    for (int k = 0; k < NK; ++k)
        #pragma unroll
        for (int t = 0; t < NKSZ; ++t)
            w[k][t] = Wp[k*NKSZ + t];

    // --- gather-sum into this wave's series -------------------------------
    const int* idx = I + ((di*NDIV + j)*NH + h)*NNCP;
    const float* xb = X + (size_t)b * NC * NL;
    const float* p0 = xb + idx[0]*NL;
    const float* p1 = xb + idx[1]*NL;
    const float* p2 = xb + idx[2]*NL;
    const float* p3 = xb + idx[3]*NL;
    const float* p4 = xb + idx[4]*NL;
    const float* p5 = xb + idx[5]*NL;

    if (j == 0) {
        #pragma unroll
        for (int c = 0; c < 4; ++c) {
            const int e = 256*c + 4*lane;
            float4 v0 = ld4(p0+e), v1 = ld4(p1+e), v2 = ld4(p2+e);
            float4 v3 = ld4(p3+e), v4 = ld4(p4+e), v5 = ld4(p5+e);
            float4 s;
            s.x = v0.x+v1.x+v2.x+v3.x+v4.x+v5.x;
            s.y = v0.y+v1.y+v2.y+v3.y+v4.y+v5.y;
            s.z = v0.z+v1.z+v2.z+v3.z+v4.z+v5.z;
            s.w = v0.w+v1.w+v2.w+v3.w+v4.w+v5.w;
            *(float4*)(lds + Sw + e) = s;
        }
    } else {
        // diff-of-gather == gather-of-diff (linearity)
        float4 sa[4];
        #pragma unroll
        for (int c = 0; c < 4; ++c) {
            const int e = 256*c + 4*lane;
            float4 v0 = ld4(p0+e), v1 = ld4(p1+e), v2 = ld4(p2+e);
            float4 v3 = ld4(p3+e), v4 = ld4(p4+e), v5 = ld4(p5+e);
            sa[c].x = v0.x+v1.x+v2.x+v3.x+v4.x+v5.x;
            sa[c].y = v0.y+v1.y+v2.y+v3.y+v4.y+v5.y;
            sa[c].z = v0.z+v1.z+v2.z+v3.z+v4.z+v5.z;
            sa[c].w = v0.w+v1.w+v2.w+v3.w+v4.w+v5.w;
        }
        #pragma unroll
        for (int c = 0; c < 4; ++c) {
            const float nxt = (c < 3) ? __shfl(sa[(c+1) & 3].x, 0, 64) : 0.f;
            const float sh  = __shfl_down(sa[c].x, 1, 64);
            const float Se4 = (lane == 63) ? nxt : sh;
            float4 df;
            df.x = sa[c].y - sa[c].x;
            df.y = sa[c].z - sa[c].y;
            df.z = sa[c].w - sa[c].z;
            df.w = Se4 - sa[c].w;
            if (c == 3 && lane == 63) df.w = 0.f;   // diff series: slot 1023 = 0
            const int e = 256*c + 4*lane;
            *(float4*)(lds + Sw + e) = df;
        }
    }
    __syncthreads();

    float    cm[NK];
    unsigned cn[NK];
    #pragma unroll
    for (int k = 0; k < NK; ++k) { cm[k] = 0.f; cn[k] = 0u; }

    const int  base    = Sw + 2*lane;                     // logical idx of pos pair
    const bool last_ok = (j == 0) || (lane != 63);        // only pos 1023/j=1 invalid

    if (d == 1) {
        // sliding 10-window per pair; all offsets compile-time (pads absorb OOB)
        const float* bp = lds + base - 4;
        #pragma unroll
        for (int c = 0; c < 8; ++c) {
            float2 q0 = *(const float2*)(bp + 128*c);
            float2 q1 = *(const float2*)(bp + 128*c + 2);
            float2 q2 = *(const float2*)(bp + 128*c + 4);
            float2 q3 = *(const float2*)(bp + 128*c + 6);
            float2 q4 = *(const float2*)(bp + 128*c + 8);
            const float win[10] = { q0.x,q0.y,q1.x,q1.y,q2.x,q2.y,q3.x,q3.y,q4.x,q4.y };
            float a0[NK], a1[NK];
            #pragma unroll
            for (int k = 0; k < NK; ++k) { a0[k] = 0.f; a1[k] = 0.f; }
            #pragma unroll
            for (int t = 0; t < NKSZ; ++t)
                #pragma unroll
                for (int k = 0; k < NK; ++k) {
                    a0[k] = fmaf(w[k][t], win[t],   a0[k]);
                    a1[k] = fmaf(w[k][t], win[t+1], a1[k]);
                }
            argbin(a0, true, cm, cn);
            argbin(a1, (c < 7) ? true : last_ok, cm, cn);
        }
    } else {
        // d even: taps for pos pair are consecutive -> one b64 per tap.
        // 9 hoisted tap pointers; per-chunk +512B becomes the ds imm offset.
        const float* tp[NKSZ];
        #pragma unroll
        for (int t = 0; t < NKSZ; ++t) tp[t] = lds + base + (t - 4) * d;
        #pragma unroll
        for (int c = 0; c < 8; ++c) {
            float2 v[NKSZ];
            #pragma unroll
            for (int t = 0; t < NKSZ; ++t) v[t] = *(const float2*)(tp[t] + 128*c);
            float a0[NK], a1[NK];
            #pragma unroll
            for (int k = 0; k < NK; ++k) { a0[k] = 0.f; a1[k] = 0.f; }
            #pragma unroll
            for (int t = 0; t < NKSZ; ++t)
                #pragma unroll
                for (int k = 0; k < NK; ++k) {
                    a0[k] = fmaf(w[k][t], v[t].x, a0[k]);
                    a1[k] = fmaf(w[k][t], v[t].y, a1[k]);
                }
            argbin(a0, true, cm, cn);
            argbin(a1, (c < 7) ? true : last_ok, cm, cn);
        }
    }

    // pack cn into 16-bit pairs (per-thread counts <= 16; reduced <= 1024)
    unsigned cp[4];
    #pragma unroll
    for (int i = 0; i < 4; ++i) cp[i] = cn[2*i] | (cn[2*i+1] << 16);

    // wave shuffle reduction over 12 registers
    #pragma unroll
    for (int s = 32; s > 0; s >>= 1) {
        #pragma unroll
        for (int k = 0; k < NK; ++k) cm[k] += __shfl_down(cm[k], s, 64);
        #pragma unroll
        for (int i = 0; i < 4; ++i)
            cp[i] += (unsigned)__shfl_down((int)cp[i], s, 64);
    }
    if (lane == 0) {
        #pragma unroll
        for (int k = 0; k < NK; ++k) red[wid][k] = cm[k];
        #pragma unroll
        for (int i = 0; i < 4; ++i) {
            red[wid][8 + 2*i] = (float)(cp[i] & 0xffffu);
            red[wid][9 + 2*i] = (float)(cp[i] >> 16);
        }
    }
    __syncthreads();

    if (tid < 64) {
        const int ws = tid >> 4, slot = tid & 15;
        const int mm = slot >> 3, k = slot & 7;
        const int ho = h4*4 + ws;
        const int z  = dj*2 + mm;                 // [max, min] per (di,j)
        out[(size_t)b*OUTPB + z*(NH*NK) + ho*NK + k] = red[ws][slot];
    }
}

extern "C" void kernel_launch(void* const* d_in, const int* in_sizes, int n_in,
                              void* d_out, int out_size, void* d_ws, size_t ws_size,
                              hipStream_t stream) {
    const float* X = (const float*)d_in[0];
    const float* W = (const float*)d_in[1];
    const int*   I = (const int*)d_in[2];
    float* out = (float*)d_out;

    const int nblocks = NB * (NDIL*NDIV) * (NH/4);   // 14336
    hydra_kernel<<<dim3(nblocks), dim3(256), 0, stream>>>(X, W, I, out);
}

// Round 5
// 164.094 us; speedup vs baseline: 1.6856x; 1.6856x over previous
//
#include <hip/hip_runtime.h>

#define NB 128
#define NC 12
#define NL 1024
#define NDIL 7
#define NDIV 2
#define NH 32
#define NK 8
#define NKSZ 9
#define NNCP 6
#define OUTPB (NDIL*NDIV*2*NH*NK)   // 7168

// LDS: [Z0 256][g0 1024][Z1 256][g1 1024][Z2 256][g2 1024][Z3 256][g3 1024][Z4 256]
// zero strips shared between adjacent waves' front/back pads
#define SER_STRIDE 1280
#define LDS_FLOATS (4*SER_STRIDE + 256)   // 5376 floats = 21504 B

__device__ __forceinline__ float4 ld4(const float* p) { return *(const float4*)p; }

// force wave-uniform value into an SGPR
__device__ __forceinline__ float sgpr(float v) {
    return __int_as_float(__builtin_amdgcn_readfirstlane(__float_as_int(v)));
}

template<int CTRL, int RM>
__device__ __forceinline__ float dppadd_f(float x) {
    int t = __builtin_amdgcn_update_dpp(0, __float_as_int(x), CTRL, RM, 0xf, false);
    return x + __int_as_float(t);
}
template<int CTRL, int RM>
__device__ __forceinline__ unsigned dppadd_u(unsigned x) {
    int t = __builtin_amdgcn_update_dpp(0, (int)x, CTRL, RM, 0xf, false);
    return x + (unsigned)t;
}
// full-wave sum; result valid on lane 63
#define RSUM_F(x) { x = dppadd_f<0x111,0xf>(x); x = dppadd_f<0x112,0xf>(x); \
                    x = dppadd_f<0x114,0xf>(x); x = dppadd_f<0x118,0xf>(x); \
                    x = dppadd_f<0x142,0xa>(x); x = dppadd_f<0x143,0xc>(x); }
#define RSUM_U(x) { x = dppadd_u<0x111,0xf>(x); x = dppadd_u<0x112,0xf>(x); \
                    x = dppadd_u<0x114,0xf>(x); x = dppadd_u<0x118,0xf>(x); \
                    x = dppadd_u<0x142,0xa>(x); x = dppadd_u<0x143,0xc>(x); }

#define Wk(k,t) wf[(k)*NKSZ+(t)]

__global__ __launch_bounds__(256) void hydra_kernel(
    const float* __restrict__ X,   // [B, C, L]
    const float* __restrict__ W,   // [NDIL, NDIV, K*H, 1, KSZ]
    const int*   __restrict__ I,   // [NDIL, NDIV, H, NCP]
    float*       __restrict__ out) // [B, 28*H*K]
{
    __shared__ float lds[LDS_FLOATS];
    __shared__ float red[4][16];

    const int bid = blockIdx.x;
    const int h4 = bid & 7;
    const int dj = (bid >> 3) % 14;
    const int b  = (bid >> 3) / 14;
    const int di = dj >> 1;
    const int j  = dj & 1;
    const int d  = 1 << di;

    const int tid  = threadIdx.x;
    const int lane = tid & 63;
    const int wid  = __builtin_amdgcn_readfirstlane(tid >> 6);
    const int h    = h4 * 4 + wid;            // wave-uniform
    const int Sw   = 256 + wid * SER_STRIDE;  // this wave's series base

    // zero the 5 shared pad strips
    #pragma unroll
    for (int z = 0; z < 5; ++z) lds[z * SER_STRIDE + tid] = 0.f;

    // --- gather-sum into this wave's series -------------------------------
    const int* idx = I + ((di*NDIV + j)*NH + h)*NNCP;
    const float* xb = X + (size_t)b * NC * NL;
    const float* p0 = xb + idx[0]*NL;
    const float* p1 = xb + idx[1]*NL;
    const float* p2 = xb + idx[2]*NL;
    const float* p3 = xb + idx[3]*NL;
    const float* p4 = xb + idx[4]*NL;
    const float* p5 = xb + idx[5]*NL;

    if (j == 0) {
        #pragma unroll
        for (int c = 0; c < 4; ++c) {
            const int e = 256*c + 4*lane;
            float4 v0 = ld4(p0+e), v1 = ld4(p1+e), v2 = ld4(p2+e);
            float4 v3 = ld4(p3+e), v4 = ld4(p4+e), v5 = ld4(p5+e);
            float4 s;
            s.x = v0.x+v1.x+v2.x+v3.x+v4.x+v5.x;
            s.y = v0.y+v1.y+v2.y+v3.y+v4.y+v5.y;
            s.z = v0.z+v1.z+v2.z+v3.z+v4.z+v5.z;
            s.w = v0.w+v1.w+v2.w+v3.w+v4.w+v5.w;
            *(float4*)(lds + Sw + e) = s;
        }
    } else {
        // diff-of-gather == gather-of-diff (linearity)
        float4 sa[4];
        #pragma unroll
        for (int c = 0; c < 4; ++c) {
            const int e = 256*c + 4*lane;
            float4 v0 = ld4(p0+e), v1 = ld4(p1+e), v2 = ld4(p2+e);
            float4 v3 = ld4(p3+e), v4 = ld4(p4+e), v5 = ld4(p5+e);
            sa[c].x = v0.x+v1.x+v2.x+v3.x+v4.x+v5.x;
            sa[c].y = v0.y+v1.y+v2.y+v3.y+v4.y+v5.y;
            sa[c].z = v0.z+v1.z+v2.z+v3.z+v4.z+v5.z;
            sa[c].w = v0.w+v1.w+v2.w+v3.w+v4.w+v5.w;
        }
        #pragma unroll
        for (int c = 0; c < 4; ++c) {
            const float nxt = (c < 3) ? __shfl(sa[(c+1) & 3].x, 0, 64) : 0.f;
            const float sh  = __shfl_down(sa[c].x, 1, 64);
            const float Se4 = (lane == 63) ? nxt : sh;
            float4 df;
            df.x = sa[c].y - sa[c].x;
            df.y = sa[c].z - sa[c].y;
            df.z = sa[c].w - sa[c].z;
            df.w = Se4 - sa[c].w;
            if (c == 3 && lane == 63) df.w = 0.f;   // diff series: slot 1023 = 0
            const int e = 256*c + 4*lane;
            *(float4*)(lds + Sw + e) = df;
        }
    }
    __syncthreads();

    // --- weights: force into SGPRs (wave-uniform h) -----------------------
    float wf[NK*NKSZ];
    {
        const float* Wp = W + (size_t)((di*NDIV + j)*(NK*NH) + h*NK) * NKSZ;
        #pragma unroll
        for (int i = 0; i < 18; ++i) {
            float4 v = ld4(Wp + 4*i);
            wf[4*i+0] = sgpr(v.x); wf[4*i+1] = sgpr(v.y);
            wf[4*i+2] = sgpr(v.z); wf[4*i+3] = sgpr(v.w);
        }
    }

    float    cm[NK];
    unsigned cn[NK];
    #pragma unroll
    for (int k = 0; k < NK; ++k) { cm[k] = 0.f; cn[k] = 0u; }

    const int  base = Sw + 2*lane;               // pos-pair index in lds
    const bool okl  = (j == 0) || (lane != 63);  // only pos 1023/j=1 invalid

#define ARGBIN(A, OK)                                                     \
    {                                                                     \
        float mx = fmaxf(fmaxf(A[0], A[1]), A[2]);                        \
        mx = fmaxf(fmaxf(mx, A[3]), A[4]);                                \
        mx = fmaxf(fmaxf(mx, A[5]), A[6]);                                \
        mx = fmaxf(mx, A[7]);                                             \
        float mn = fminf(fminf(A[0], A[1]), A[2]);                        \
        mn = fminf(fminf(mn, A[3]), A[4]);                                \
        mn = fminf(fminf(mn, A[5]), A[6]);                                \
        mn = fminf(mn, A[7]);                                             \
        if (OK) {                                                         \
            _Pragma("unroll")                                             \
            for (int k = 0; k < NK; ++k) {                                \
                cm[k] += (A[k] == mx) ? A[k] : 0.f;                       \
                cn[k] += (A[k] == mn) ? 1u : 0u;                          \
            }                                                             \
        }                                                                 \
    }

    if (d == 1) {
        for (int c = 0; c < 8; ++c) {
            const float* bp = lds + base - 4 + 128*c;
            float2 q0 = *(const float2*)(bp);
            float2 q1 = *(const float2*)(bp + 2);
            float2 q2 = *(const float2*)(bp + 4);
            float2 q3 = *(const float2*)(bp + 6);
            float2 q4 = *(const float2*)(bp + 8);
            const float win[10] = { q0.x,q0.y,q1.x,q1.y,q2.x,q2.y,q3.x,q3.y,q4.x,q4.y };
            float a0[NK], a1[NK];
            #pragma unroll
            for (int k = 0; k < NK; ++k) { a0[k] = 0.f; a1[k] = 0.f; }
            #pragma unroll
            for (int t = 0; t < NKSZ; ++t)
                #pragma unroll
                for (int k = 0; k < NK; ++k) {
                    a0[k] = fmaf(Wk(k,t), win[t],   a0[k]);
                    a1[k] = fmaf(Wk(k,t), win[t+1], a1[k]);
                }
            ARGBIN(a0, true);
            ARGBIN(a1, (c != 7) || okl);
        }
    } else {
        for (int c = 0; c < 8; ++c) {
            float2 v[NKSZ];
            #pragma unroll
            for (int t = 0; t < NKSZ; ++t)
                v[t] = *(const float2*)(lds + base + (t - 4)*d + 128*c);
            float a0[NK], a1[NK];
            #pragma unroll
            for (int k = 0; k < NK; ++k) { a0[k] = 0.f; a1[k] = 0.f; }
            #pragma unroll
            for (int t = 0; t < NKSZ; ++t)
                #pragma unroll
                for (int k = 0; k < NK; ++k) {
                    a0[k] = fmaf(Wk(k,t), v[t].x, a0[k]);
                    a1[k] = fmaf(Wk(k,t), v[t].y, a1[k]);
                }
            ARGBIN(a0, true);
            ARGBIN(a1, (c != 7) || okl);
        }
    }
#undef ARGBIN

    // pack counts (each half-word sum <= 1024, no carry crossing)
    unsigned cp[4];
    #pragma unroll
    for (int i = 0; i < 4; ++i) cp[i] = cn[2*i] | (cn[2*i+1] << 16);

    // DPP wave sums (VALU-only), results land on lane 63
    #pragma unroll
    for (int k = 0; k < NK; ++k) RSUM_F(cm[k]);
    #pragma unroll
    for (int i = 0; i < 4; ++i) RSUM_U(cp[i]);

    if (lane == 63) {
        #pragma unroll
        for (int k = 0; k < NK; ++k) red[wid][k] = cm[k];
        #pragma unroll
        for (int i = 0; i < 4; ++i) {
            red[wid][8 + 2*i] = (float)(cp[i] & 0xffffu);
            red[wid][9 + 2*i] = (float)(cp[i] >> 16);
        }
    }
    __syncthreads();

    if (tid < 64) {
        const int ws = tid >> 4, slot = tid & 15;
        const int mm = slot >> 3, k = slot & 7;
        const int ho = h4*4 + ws;
        const int z  = dj*2 + mm;                 // [max, min] per (di,j)
        out[(size_t)b*OUTPB + z*(NH*NK) + ho*NK + k] = red[ws][slot];
    }
}

extern "C" void kernel_launch(void* const* d_in, const int* in_sizes, int n_in,
                              void* d_out, int out_size, void* d_ws, size_t ws_size,
                              hipStream_t stream) {
    const float* X = (const float*)d_in[0];
    const float* W = (const float*)d_in[1];
    const int*   I = (const int*)d_in[2];
    float* out = (float*)d_out;

    const int nblocks = NB * (NDIL*NDIV) * (NH/4);   // 14336
    hydra_kernel<<<dim3(nblocks), dim3(256), 0, stream>>>(X, W, I, out);
}